// Round 13
// baseline (224.127 us; speedup 1.0000x reference)
//
#include <hip/hip_runtime.h>

#define N_NODES 50000
#define N_EDGES 800000
#define D 128
#define ROWS 16
#define BCAP 255          // tier2/3: slot cap in a row's 512B out budget
#define RCAP 32           // tier1: slots per replica sub-region (8*32=256)
#define LCAP 64           // LDS-staged slots per row, power of 2 (deg max ~45)
#define ESC_BLOCKS 3125   // 1 edge/thread: 3125*256 = 800000 exactly
#define XCONV_BLOCKS 3125 // 3125*256*8 = 6.4M floats = x converted to bf16
#define NORM_BLOCKS 196   // tier3 only
#define WSPLIT_BLOCKS 128 // 128*256 = 32768 = 2*D*D
// tier2 layout (round-12 proven)
#define XB_OFF 200064
#define WHI_OFF 13000064
#define WS1_NEEDED 13131136ull
// tier1 layout (replicated cursors)
#define XB2_OFF 1600064
#define WHI2_OFF 14400064
#define WS2_NEEDED 14531136ull

typedef int   v4i __attribute__((ext_vector_type(4)));
typedef float v4f __attribute__((ext_vector_type(4)));

// tier1 d_ws: [0,1.6M) deg8 (int[50000][8], cursor k=e&7; true deg = sum of 8;
//             counters run past RCAP so sums stay exact)
//             [1600064,+12.8M) xb ; [14400064,+131072) whi/wlo planes
// d_out: per-row 512B = 8 replica sub-regions x 32 ushort slots; fused reads
//        ONLY ITS OWN rows' slots then overwrites them => no cross-block hazard.
// Round-9 lesson: MFMA B operands come from MEMORY loads only (waitcnt slack).

// ---- round-to-nearest-even f32 -> bf16 helpers ------------------------------
__device__ __forceinline__ unsigned short bf_rne(float v) {
    unsigned u = __float_as_uint(v);
    u += 0x7FFFu + ((u >> 16) & 1u);
    return (unsigned short)(u >> 16);
}
__device__ __forceinline__ float bf_up(unsigned short h) {
    return __uint_as_float((unsigned)h << 16);
}
__device__ __forceinline__ void split_pack(float a, float b, unsigned& hw, unsigned& lw) {
    unsigned short ha = bf_rne(a);
    unsigned short hb = bf_rne(b);
    unsigned short la = bf_rne(a - bf_up(ha));
    unsigned short lb = bf_rne(b - bf_up(hb));
    hw = (unsigned)ha | ((unsigned)hb << 16);
    lw = (unsigned)la | ((unsigned)lb << 16);
}
__device__ __forceinline__ unsigned pack2(float a, float b) {
    return (unsigned)bf_rne(a) | ((unsigned)bf_rne(b) << 16);
}

// ---- tier1 K1: replicated-cursor scatter + xconv + wsplit -------------------
__global__ void scatter8_kernel(const int* __restrict__ src, const int* __restrict__ dst,
                                int* __restrict__ deg8, unsigned short* outSlots,
                                const float* __restrict__ x, unsigned short* __restrict__ xb,
                                const float* __restrict__ w1, const float* __restrict__ w2,
                                unsigned short* __restrict__ whi1, unsigned short* __restrict__ wlo1,
                                unsigned short* __restrict__ whi2, unsigned short* __restrict__ wlo2) {
    int b = blockIdx.x, t = threadIdx.x;
    if (b < ESC_BLOCKS) {
        int e = b * 256 + t;  // 3125*256 == N_EDGES exactly
        int s = src[e], d = dst[e];
        int k = e & 7;
        int p = atomicAdd(&deg8[(size_t)d * 8 + k], 1);  // ~2 ops/address
        if (p < RCAP) outSlots[(size_t)d * 256 + k * RCAP + p] = (unsigned short)s;
    } else if (b < ESC_BLOCKS + XCONV_BLOCKS) {
        int i = (b - ESC_BLOCKS) * 256 + t;  // 8 floats each
        float4 a = *(const float4*)(x + (size_t)8 * i);
        float4 c = *(const float4*)(x + (size_t)8 * i + 4);
        uint4 o;
        o.x = pack2(a.x, a.y);
        o.y = pack2(a.z, a.w);
        o.z = pack2(c.x, c.y);
        o.w = pack2(c.z, c.w);
        *(uint4*)(xb + (size_t)8 * i) = o;
    } else {
        int m = (b - ESC_BLOCKS - XCONV_BLOCKS) * 256 + t;
        int sel = m >> 14;
        int j = m & 16383;
        float v = sel ? w2[j] : w1[j];
        unsigned short h = bf_rne(v);
        unsigned short lo = bf_rne(v - bf_up(h));
        if (sel) { whi2[j] = h; wlo2[j] = lo; }
        else     { whi1[j] = h; wlo1[j] = lo; }
    }
}

// ---- tier2 K1 (round-12 proven): single-cursor scatter + xconv + wsplit -----
__global__ void scatter_kernel(const int* __restrict__ src, const int* __restrict__ dst,
                               int* __restrict__ deg, unsigned short* outSlots,
                               const float* __restrict__ x, unsigned short* __restrict__ xb,
                               const float* __restrict__ w1, const float* __restrict__ w2,
                               unsigned short* __restrict__ whi1, unsigned short* __restrict__ wlo1,
                               unsigned short* __restrict__ whi2, unsigned short* __restrict__ wlo2) {
    int b = blockIdx.x, t = threadIdx.x;
    if (b < ESC_BLOCKS) {
        int e = b * 256 + t;
        int s = src[e], d = dst[e];
        int p = atomicAdd(&deg[d], 1);
        if (p < BCAP) outSlots[(size_t)d * 256 + p] = (unsigned short)s;
    } else if (b < ESC_BLOCKS + XCONV_BLOCKS) {
        int i = (b - ESC_BLOCKS) * 256 + t;
        float4 a = *(const float4*)(x + (size_t)8 * i);
        float4 c = *(const float4*)(x + (size_t)8 * i + 4);
        uint4 o;
        o.x = pack2(a.x, a.y);
        o.y = pack2(a.z, a.w);
        o.z = pack2(c.x, c.y);
        o.w = pack2(c.z, c.w);
        *(uint4*)(xb + (size_t)8 * i) = o;
    } else {
        int m = (b - ESC_BLOCKS - XCONV_BLOCKS) * 256 + t;
        int sel = m >> 14;
        int j = m & 16383;
        float v = sel ? w2[j] : w1[j];
        unsigned short h = bf_rne(v);
        unsigned short lo = bf_rne(v - bf_up(h));
        if (sel) { whi2[j] = h; wlo2[j] = lo; }
        else     { whi1[j] = h; wlo1[j] = lo; }
    }
}

// ---- prep (tier3 only): normArr + weight split into dstbuf ------------------
__global__ void prep_kernel(const int* __restrict__ deg, float* __restrict__ normArr,
                            const float* __restrict__ w1, const float* __restrict__ w2,
                            unsigned short* __restrict__ whi1, unsigned short* __restrict__ wlo1,
                            unsigned short* __restrict__ whi2, unsigned short* __restrict__ wlo2) {
    int b = blockIdx.x, t = threadIdx.x;
    if (b < NORM_BLOCKS) {
        int n = b * 256 + t;
        if (n < N_NODES)
            normArr[n] = rsqrtf(fmaxf((float)deg[n], 1.0f));
    } else {
        int m = (b - NORM_BLOCKS) * 256 + t;
        int sel = m >> 14;
        int j = m & 16383;
        float v = sel ? w2[j] : w1[j];
        unsigned short h = bf_rne(v);
        unsigned short lo = bf_rne(v - bf_up(h));
        if (sel) { whi2[j] = h; wlo2[j] = lo; }
        else     { whi1[j] = h; wlo1[j] = lo; }
    }
}

// ======== MFMA MLP phase (round-7/10 proven), shared by all fused paths ======
// 4 waves: wave wv -> col 32-block cb=wv*32 (all 16 rows in the one tile).
// mfma_f32_16x16x32_bf16: A row = lane&15, k = (lane>>4)*8 + i (8 consecutive);
// B col = lane&15, same k;  D col = lane&15, row = (lane>>4)*4 + reg.
#define MLP_BODY                                                               \
    int wv = t >> 6;                                                           \
    int cb = wv << 5;                                                          \
    int l15 = l & 15;                                                          \
    int kq = l >> 4;                                                           \
    const char* phiA = (const char*)&Ahi[l15][0];                              \
    const char* ploA = (const char*)&Alo[l15][0];                              \
    v4i ahi[4], alo[4];                                                        \
_Pragma("unroll")                                                              \
    for (int kt = 0; kt < 4; ++kt) {                                           \
        int off = ((((kt << 2) | kq) ^ l15) << 4);                             \
        ahi[kt] = *(const v4i*)(phiA + off);                                   \
        alo[kt] = *(const v4i*)(ploA + off);                                   \
    }                                                                          \
    __syncthreads();                                                           \
_Pragma("unroll")                                                              \
    for (int ct = 0; ct < 2; ++ct) {                                           \
        int c = cb + (ct << 4) + l15;                                          \
        float bv = b1[c];                                                      \
        v4f acc = {bv, bv, bv, bv};                                            \
        const unsigned short* wh = whi1 + c * D + (kq << 3);                   \
        const unsigned short* wl = wlo1 + c * D + (kq << 3);                   \
_Pragma("unroll")                                                              \
        for (int kt = 0; kt < 4; ++kt) {                                       \
            v4i bh = *(const v4i*)(wh + (kt << 5));                            \
            v4i bl = *(const v4i*)(wl + (kt << 5));                            \
            asm volatile("v_mfma_f32_16x16x32_bf16 %0, %1, %2, %0" : "+v"(acc) : "v"(ahi[kt]), "v"(bh)); \
            asm volatile("v_mfma_f32_16x16x32_bf16 %0, %1, %2, %0" : "+v"(acc) : "v"(alo[kt]), "v"(bh)); \
            asm volatile("v_mfma_f32_16x16x32_bf16 %0, %1, %2, %0" : "+v"(acc) : "v"(ahi[kt]), "v"(bl)); \
        }                                                                      \
        asm volatile("s_nop 7\n\ts_nop 7" : "+v"(acc));                        \
_Pragma("unroll")                                                              \
        for (int r = 0; r < 4; ++r) {                                          \
            float v = fmaxf(acc[r], 0.0f);                                     \
            unsigned short hv = bf_rne(v);                                     \
            unsigned short lv = bf_rne(v - bf_up(hv));                         \
            int ro = (kq << 2) + r;                                            \
            int byte = (2 * c) ^ ((ro & 15) << 4);                             \
            *(unsigned short*)((char*)&Ahi[ro][0] + byte) = hv;                \
            *(unsigned short*)((char*)&Alo[ro][0] + byte) = lv;                \
        }                                                                      \
    }                                                                          \
    __syncthreads();                                                           \
_Pragma("unroll")                                                              \
    for (int kt = 0; kt < 4; ++kt) {                                           \
        int off = ((((kt << 2) | kq) ^ l15) << 4);                             \
        ahi[kt] = *(const v4i*)(phiA + off);                                   \
        alo[kt] = *(const v4i*)(ploA + off);                                   \
    }                                                                          \
_Pragma("unroll")                                                              \
    for (int ct = 0; ct < 2; ++ct) {                                           \
        int c = cb + (ct << 4) + l15;                                          \
        float bv = b2[c];                                                      \
        v4f acc = {bv, bv, bv, bv};                                            \
        const unsigned short* wh = whi2 + c * D + (kq << 3);                   \
        const unsigned short* wl = wlo2 + c * D + (kq << 3);                   \
_Pragma("unroll")                                                              \
        for (int kt = 0; kt < 4; ++kt) {                                       \
            v4i bh = *(const v4i*)(wh + (kt << 5));                            \
            v4i bl = *(const v4i*)(wl + (kt << 5));                            \
            asm volatile("v_mfma_f32_16x16x32_bf16 %0, %1, %2, %0" : "+v"(acc) : "v"(ahi[kt]), "v"(bh)); \
            asm volatile("v_mfma_f32_16x16x32_bf16 %0, %1, %2, %0" : "+v"(acc) : "v"(alo[kt]), "v"(bh)); \
            asm volatile("v_mfma_f32_16x16x32_bf16 %0, %1, %2, %0" : "+v"(acc) : "v"(ahi[kt]), "v"(bl)); \
        }                                                                      \
        asm volatile("s_nop 7\n\ts_nop 7" : "+v"(acc));                        \
_Pragma("unroll")                                                              \
        for (int r = 0; r < 4; ++r) {                                          \
            int ro = row_base + (kq << 2) + r;                                 \
            if (ro < N_NODES)                                                  \
                io[(size_t)ro * D + c] = fmaxf(acc[r], 0.0f);                  \
        }                                                                      \
    }

// shared bf16 gather chunk over staged colsL/ncolL
#define BF16_CHUNK8(RR, J)                                                     \
    {                                                                          \
        int s0 = colsL[RR][J + 0], s1 = colsL[RR][J + 1], s2 = colsL[RR][J + 2], s3 = colsL[RR][J + 3]; \
        int s4 = colsL[RR][J + 4], s5 = colsL[RR][J + 5], s6 = colsL[RR][J + 6], s7 = colsL[RR][J + 7]; \
        float n0 = ncolL[RR][J + 0], n1 = ncolL[RR][J + 1], n2 = ncolL[RR][J + 2], n3 = ncolL[RR][J + 3]; \
        float n4 = ncolL[RR][J + 4], n5 = ncolL[RR][J + 5], n6 = ncolL[RR][J + 6], n7 = ncolL[RR][J + 7]; \
        uint2 v0 = *(const uint2*)(xb + (size_t)s0 * D + 4 * tx);              \
        uint2 v1 = *(const uint2*)(xb + (size_t)s1 * D + 4 * tx);              \
        uint2 v2 = *(const uint2*)(xb + (size_t)s2 * D + 4 * tx);              \
        uint2 v3 = *(const uint2*)(xb + (size_t)s3 * D + 4 * tx);              \
        uint2 v4 = *(const uint2*)(xb + (size_t)s4 * D + 4 * tx);              \
        uint2 v5 = *(const uint2*)(xb + (size_t)s5 * D + 4 * tx);              \
        uint2 v6 = *(const uint2*)(xb + (size_t)s6 * D + 4 * tx);              \
        uint2 v7 = *(const uint2*)(xb + (size_t)s7 * D + 4 * tx);              \
        acc.x += __uint_as_float(v0.x << 16) * n0 + __uint_as_float(v1.x << 16) * n1 \
               + __uint_as_float(v2.x << 16) * n2 + __uint_as_float(v3.x << 16) * n3 \
               + __uint_as_float(v4.x << 16) * n4 + __uint_as_float(v5.x << 16) * n5 \
               + __uint_as_float(v6.x << 16) * n6 + __uint_as_float(v7.x << 16) * n7; \
        acc.y += __uint_as_float(v0.x & 0xffff0000u) * n0 + __uint_as_float(v1.x & 0xffff0000u) * n1 \
               + __uint_as_float(v2.x & 0xffff0000u) * n2 + __uint_as_float(v3.x & 0xffff0000u) * n3 \
               + __uint_as_float(v4.x & 0xffff0000u) * n4 + __uint_as_float(v5.x & 0xffff0000u) * n5 \
               + __uint_as_float(v6.x & 0xffff0000u) * n6 + __uint_as_float(v7.x & 0xffff0000u) * n7; \
        acc.z += __uint_as_float(v0.y << 16) * n0 + __uint_as_float(v1.y << 16) * n1 \
               + __uint_as_float(v2.y << 16) * n2 + __uint_as_float(v3.y << 16) * n3 \
               + __uint_as_float(v4.y << 16) * n4 + __uint_as_float(v5.y << 16) * n5 \
               + __uint_as_float(v6.y << 16) * n6 + __uint_as_float(v7.y << 16) * n7; \
        acc.w += __uint_as_float(v0.y & 0xffff0000u) * n0 + __uint_as_float(v1.y & 0xffff0000u) * n1 \
               + __uint_as_float(v2.y & 0xffff0000u) * n2 + __uint_as_float(v3.y & 0xffff0000u) * n3 \
               + __uint_as_float(v4.y & 0xffff0000u) * n4 + __uint_as_float(v5.y & 0xffff0000u) * n5 \
               + __uint_as_float(v6.y & 0xffff0000u) * n6 + __uint_as_float(v7.y & 0xffff0000u) * n7; \
    }

// -------- tier1 fused: replica-compacted staging + bf16 gather + MFMA --------
__global__ __launch_bounds__(256) void fused_gather_mlp_rep(
    const unsigned short* __restrict__ xb,
    const unsigned short* slotsIn,      // aliases io — NO restrict
    const int* __restrict__ deg8,
    float* io,                          // aliases slotsIn — NO restrict
    const unsigned short* __restrict__ whi1, const unsigned short* __restrict__ wlo1,
    const float* __restrict__ b1,
    const unsigned short* __restrict__ whi2, const unsigned short* __restrict__ wlo2,
    const float* __restrict__ b2) {
    __shared__ __align__(16) unsigned short Ahi[ROWS][D];
    __shared__ __align__(16) unsigned short Alo[ROWS][D];
    __shared__ unsigned short colsL[ROWS][LCAP];
    __shared__ float ncolL[ROWS][LCAP];
    __shared__ unsigned char cntL[ROWS][8];   // capped replica counts
    __shared__ unsigned char offL[ROWS][8];   // replica prefix within row
    __shared__ int dcapL[ROWS];
    __shared__ float nrL[ROWS];
    __shared__ int nextRow;
    int row_base = blockIdx.x * ROWS;
    int t = threadIdx.x;
    int tx = t & 31;
    int l = t & 63;

    // zero pads (fill only writes valid entries)
    for (int i = t; i < ROWS * LCAP; i += 256) {
        colsL[i >> 6][i & (LCAP - 1)] = 0;
        ncolL[i >> 6][i & (LCAP - 1)] = 0.f;
    }
    if (t == 0) nextRow = 0;
    if (t < ROWS) {  // per-row: 8 replica counters -> counts, offsets, norm
        const int4* p = (const int4*)(deg8 + (size_t)(row_base + t) * 8);
        int4 a = p[0], b = p[1];
        int cc[8] = {a.x, a.y, a.z, a.w, b.x, b.y, b.z, b.w};
        int tru = 0, off = 0;
#pragma unroll
        for (int k = 0; k < 8; ++k) {
            tru += cc[k];
            int c = min(cc[k], RCAP);
            cntL[t][k] = (unsigned char)c;
            offL[t][k] = (unsigned char)off;
            off += c;
        }
        dcapL[t] = off;
        nrL[t] = rsqrtf(fmaxf((float)tru, 1.0f));
    }
    __syncthreads();

    // compact replica sub-lists into contiguous colsL + inline src norms
    for (int e2 = t; e2 < ROWS * 256; e2 += 256) {
        int r = e2 >> 8, slot = e2 & 255, k = slot >> 5, j = slot & 31;
        if (j < (int)cntL[r][k]) {
            int s = slotsIn[(size_t)(row_base + r) * 256 + slot];
            int idx = (int)offL[r][k] + j;
            if (idx < LCAP) {
                colsL[r][idx] = (unsigned short)s;
                const int4* q = (const int4*)(deg8 + (size_t)s * 8);
                int4 a = q[0], b = q[1];
                int sd = a.x + a.y + a.z + a.w + b.x + b.y + b.z + b.w;
                ncolL[r][idx] = rsqrtf(fmaxf((float)sd, 1.0f));
            }
        }
    }
    __syncthreads();

    // gather: 8 groups of 32 lanes, work-stealing over 16 rows
    for (;;) {
        int rr;
        if (tx == 0) rr = atomicAdd(&nextRow, 1);
        rr = __shfl(rr, l & 32);
        if (rr >= ROWS) break;
        float nr = nrL[rr];
        float4 acc = make_float4(0.f, 0.f, 0.f, 0.f);
        int jend = min(dcapL[rr], LCAP);
        for (int j = 0; j < jend; j += 8) BF16_CHUNK8(rr, j)  // zero-pads mask tail
        if (dcapL[rr] > LCAP) {  // astronomically rare overflow walk
            for (int slot = 0; slot < 256; ++slot) {
                int k = slot >> 5, j = slot & 31;
                if (j < (int)cntL[rr][k] && (int)offL[rr][k] + j >= LCAP) {
                    int s = slotsIn[(size_t)(row_base + rr) * 256 + slot];
                    const int4* q = (const int4*)(deg8 + (size_t)s * 8);
                    int4 a = q[0], b = q[1];
                    int sd = a.x + a.y + a.z + a.w + b.x + b.y + b.z + b.w;
                    float nv = rsqrtf(fmaxf((float)sd, 1.0f));
                    uint2 v = *(const uint2*)(xb + (size_t)s * D + 4 * tx);
                    acc.x += __uint_as_float(v.x << 16) * nv;
                    acc.y += __uint_as_float(v.x & 0xffff0000u) * nv;
                    acc.z += __uint_as_float(v.y << 16) * nv;
                    acc.w += __uint_as_float(v.y & 0xffff0000u) * nv;
                }
            }
        }
        acc.x *= nr; acc.y *= nr; acc.z *= nr; acc.w *= nr;
        unsigned hw0, lw0, hw1, lw1;
        split_pack(acc.x, acc.y, hw0, lw0);
        split_pack(acc.z, acc.w, hw1, lw1);
        int byte = (8 * tx) ^ ((rr & 15) << 4);
        *(uint2*)((char*)&Ahi[rr][0] + byte) = make_uint2(hw0, hw1);
        *(uint2*)((char*)&Alo[rr][0] + byte) = make_uint2(lw0, lw1);
    }
    __syncthreads();

    MLP_BODY
}

// -------- tier2 fused (round-12 proven): single-cursor, inline rsqrt ---------
__global__ __launch_bounds__(256) void fused_gather_mlp_bf16(
    const unsigned short* __restrict__ xb,
    const unsigned short* slotsIn,      // aliases io — NO restrict
    const int* __restrict__ deg,
    float* io,                          // aliases slotsIn — NO restrict
    const unsigned short* __restrict__ whi1, const unsigned short* __restrict__ wlo1,
    const float* __restrict__ b1,
    const unsigned short* __restrict__ whi2, const unsigned short* __restrict__ wlo2,
    const float* __restrict__ b2) {
    __shared__ __align__(16) unsigned short Ahi[ROWS][D];
    __shared__ __align__(16) unsigned short Alo[ROWS][D];
    __shared__ unsigned short colsL[ROWS][LCAP];
    __shared__ float ncolL[ROWS][LCAP];
    __shared__ int degL[ROWS];
    __shared__ int nextRow;
    int row_base = blockIdx.x * ROWS;
    int t = threadIdx.x;
    int tx = t & 31;
    int l = t & 63;

    if (t < ROWS) degL[t] = deg[row_base + t];
    if (t == ROWS) nextRow = 0;
    __syncthreads();

    for (int e2 = t; e2 < ROWS * LCAP; e2 += 256) {
        int r = e2 >> 6;
        int j = e2 & (LCAP - 1);
        if (j < degL[r]) {
            int s = slotsIn[(size_t)(row_base + r) * 256 + j];
            colsL[r][j] = (unsigned short)s;
            ncolL[r][j] = rsqrtf(fmaxf((float)deg[s], 1.0f));
        } else {
            colsL[r][j] = 0;
            ncolL[r][j] = 0.f;
        }
    }
    __syncthreads();

    for (;;) {
        int rr;
        if (tx == 0) rr = atomicAdd(&nextRow, 1);
        rr = __shfl(rr, l & 32);
        if (rr >= ROWS) break;
        int dr = degL[rr];
        float nr = rsqrtf(fmaxf((float)dr, 1.0f));
        float4 acc = make_float4(0.f, 0.f, 0.f, 0.f);
        int jend = min(dr, LCAP);
        for (int j = 0; j < jend; j += 8) BF16_CHUNK8(rr, j)
        if (dr > LCAP) {
            int je = min(dr, BCAP);
            for (int j = LCAP; j < je; ++j) {
                int s = slotsIn[(size_t)(row_base + rr) * 256 + j];
                float nv = rsqrtf(fmaxf((float)deg[s], 1.0f));
                uint2 v = *(const uint2*)(xb + (size_t)s * D + 4 * tx);
                acc.x += __uint_as_float(v.x << 16) * nv;
                acc.y += __uint_as_float(v.x & 0xffff0000u) * nv;
                acc.z += __uint_as_float(v.y << 16) * nv;
                acc.w += __uint_as_float(v.y & 0xffff0000u) * nv;
            }
        }
        acc.x *= nr; acc.y *= nr; acc.z *= nr; acc.w *= nr;
        unsigned hw0, lw0, hw1, lw1;
        split_pack(acc.x, acc.y, hw0, lw0);
        split_pack(acc.z, acc.w, hw1, lw1);
        int byte = (8 * tx) ^ ((rr & 15) << 4);
        *(uint2*)((char*)&Ahi[rr][0] + byte) = make_uint2(hw0, hw1);
        *(uint2*)((char*)&Alo[rr][0] + byte) = make_uint2(lw0, lw1);
    }
    __syncthreads();

    MLP_BODY
}

// -------- tier3 fused (round-10 proven): f32 x, normArr ----------------------
__global__ __launch_bounds__(256) void fused_gather_mlp_f32(
    const float* __restrict__ x,
    const unsigned short* slotsIn,      // aliases io — NO restrict
    const float* __restrict__ normArr, const int* __restrict__ deg,
    float* io,                          // aliases slotsIn — NO restrict
    const unsigned short* __restrict__ whi1, const unsigned short* __restrict__ wlo1,
    const float* __restrict__ b1,
    const unsigned short* __restrict__ whi2, const unsigned short* __restrict__ wlo2,
    const float* __restrict__ b2) {
    __shared__ __align__(16) unsigned short Ahi[ROWS][D];
    __shared__ __align__(16) unsigned short Alo[ROWS][D];
    __shared__ unsigned short colsL[ROWS][LCAP];
    __shared__ float ncolL[ROWS][LCAP];
    __shared__ int degL[ROWS];
    __shared__ int nextRow;
    int row_base = blockIdx.x * ROWS;
    int t = threadIdx.x;
    int tx = t & 31;
    int l = t & 63;

    if (t < ROWS) degL[t] = deg[row_base + t];
    if (t == ROWS) nextRow = 0;
    __syncthreads();

    for (int e2 = t; e2 < ROWS * LCAP; e2 += 256) {
        int r = e2 >> 6;
        int j = e2 & (LCAP - 1);
        if (j < degL[r]) {
            int s = slotsIn[(size_t)(row_base + r) * 256 + j];
            colsL[r][j] = (unsigned short)s;
            ncolL[r][j] = normArr[s];
        } else {
            colsL[r][j] = 0;
            ncolL[r][j] = 0.f;
        }
    }
    __syncthreads();

    for (;;) {
        int rr;
        if (tx == 0) rr = atomicAdd(&nextRow, 1);
        rr = __shfl(rr, l & 32);
        if (rr >= ROWS) break;
        int dr = degL[rr];
        float nr = rsqrtf(fmaxf((float)dr, 1.0f));
        float4 acc = make_float4(0.f, 0.f, 0.f, 0.f);
        int jend = min(dr, LCAP);
        for (int j = 0; j < jend; j += 8) {
            int s0 = colsL[rr][j + 0], s1 = colsL[rr][j + 1], s2 = colsL[rr][j + 2], s3 = colsL[rr][j + 3];
            int s4 = colsL[rr][j + 4], s5 = colsL[rr][j + 5], s6 = colsL[rr][j + 6], s7 = colsL[rr][j + 7];
            float n0 = ncolL[rr][j + 0], n1 = ncolL[rr][j + 1], n2 = ncolL[rr][j + 2], n3 = ncolL[rr][j + 3];
            float n4 = ncolL[rr][j + 4], n5 = ncolL[rr][j + 5], n6 = ncolL[rr][j + 6], n7 = ncolL[rr][j + 7];
            float4 x0 = *(const float4*)(x + (size_t)s0 * D + 4 * tx);
            float4 x1 = *(const float4*)(x + (size_t)s1 * D + 4 * tx);
            float4 x2 = *(const float4*)(x + (size_t)s2 * D + 4 * tx);
            float4 x3 = *(const float4*)(x + (size_t)s3 * D + 4 * tx);
            float4 x4 = *(const float4*)(x + (size_t)s4 * D + 4 * tx);
            float4 x5 = *(const float4*)(x + (size_t)s5 * D + 4 * tx);
            float4 x6 = *(const float4*)(x + (size_t)s6 * D + 4 * tx);
            float4 x7 = *(const float4*)(x + (size_t)s7 * D + 4 * tx);
            acc.x += x0.x * n0 + x1.x * n1 + x2.x * n2 + x3.x * n3
                   + x4.x * n4 + x5.x * n5 + x6.x * n6 + x7.x * n7;
            acc.y += x0.y * n0 + x1.y * n1 + x2.y * n2 + x3.y * n3
                   + x4.y * n4 + x5.y * n5 + x6.y * n6 + x7.y * n7;
            acc.z += x0.z * n0 + x1.z * n1 + x2.z * n2 + x3.z * n3
                   + x4.z * n4 + x5.z * n5 + x6.z * n6 + x7.z * n7;
            acc.w += x0.w * n0 + x1.w * n1 + x2.w * n2 + x3.w * n3
                   + x4.w * n4 + x5.w * n5 + x6.w * n6 + x7.w * n7;
        }
        if (dr > LCAP) {
            int je = min(dr, BCAP);
            for (int j = LCAP; j < je; ++j) {
                int s = slotsIn[(size_t)(row_base + rr) * 256 + j];
                float nv = normArr[s];
                float4 xv = *(const float4*)(x + (size_t)s * D + 4 * tx);
                acc.x += xv.x * nv; acc.y += xv.y * nv;
                acc.z += xv.z * nv; acc.w += xv.w * nv;
            }
        }
        acc.x *= nr; acc.y *= nr; acc.z *= nr; acc.w *= nr;
        unsigned hw0, lw0, hw1, lw1;
        split_pack(acc.x, acc.y, hw0, lw0);
        split_pack(acc.z, acc.w, hw1, lw1);
        int byte = (8 * tx) ^ ((rr & 15) << 4);
        *(uint2*)((char*)&Ahi[rr][0] + byte) = make_uint2(hw0, hw1);
        *(uint2*)((char*)&Alo[rr][0] + byte) = make_uint2(lw0, lw1);
    }
    __syncthreads();

    MLP_BODY
}

extern "C" void kernel_launch(void* const* d_in, const int* in_sizes, int n_in,
                              void* d_out, int out_size, void* d_ws, size_t ws_size,
                              hipStream_t stream) {
    const float* x      = (const float*)d_in[0];
    const int*   src    = (const int*)d_in[1];
    int*         dstbuf = (int*)d_in[2];
    const float* w_conv = (const float*)d_in[3];
    const float* b_conv = (const float*)d_in[4];
    const float* w_lin  = (const float*)d_in[5];
    const float* b_lin  = (const float*)d_in[6];

    if (ws_size >= WS2_NEEDED) {
        // tier1: replicated cursors
        int* deg8 = (int*)d_ws;
        unsigned short* xb = (unsigned short*)((char*)d_ws + XB2_OFF);
        unsigned short* whi1 = (unsigned short*)((char*)d_ws + WHI2_OFF);
        unsigned short* wlo1 = (unsigned short*)((char*)d_ws + WHI2_OFF + 32768);
        unsigned short* whi2 = (unsigned short*)((char*)d_ws + WHI2_OFF + 65536);
        unsigned short* wlo2 = (unsigned short*)((char*)d_ws + WHI2_OFF + 98304);
        hipMemsetAsync(deg8, 0, (size_t)N_NODES * 8 * sizeof(int), stream);
        scatter8_kernel<<<ESC_BLOCKS + XCONV_BLOCKS + WSPLIT_BLOCKS, 256, 0, stream>>>(
            src, (const int*)dstbuf, deg8, (unsigned short*)d_out, x, xb,
            w_conv, w_lin, whi1, wlo1, whi2, wlo2);
        fused_gather_mlp_rep<<<N_NODES / ROWS, 256, 0, stream>>>(
            xb, (const unsigned short*)d_out, deg8, (float*)d_out,
            whi1, wlo1, b_conv, whi2, wlo2, b_lin);
    } else if (ws_size >= WS1_NEEDED) {
        // tier2: round-12 proven path
        int* deg = (int*)d_ws;
        unsigned short* xb = (unsigned short*)((char*)d_ws + XB_OFF);
        unsigned short* whi1 = (unsigned short*)((char*)d_ws + WHI_OFF);
        unsigned short* wlo1 = (unsigned short*)((char*)d_ws + WHI_OFF + 32768);
        unsigned short* whi2 = (unsigned short*)((char*)d_ws + WHI_OFF + 65536);
        unsigned short* wlo2 = (unsigned short*)((char*)d_ws + WHI_OFF + 98304);
        hipMemsetAsync(deg, 0, (size_t)N_NODES * sizeof(int), stream);
        scatter_kernel<<<ESC_BLOCKS + XCONV_BLOCKS + WSPLIT_BLOCKS, 256, 0, stream>>>(
            src, (const int*)dstbuf, deg, (unsigned short*)d_out, x, xb,
            w_conv, w_lin, whi1, wlo1, whi2, wlo2);
        fused_gather_mlp_bf16<<<N_NODES / ROWS, 256, 0, stream>>>(
            xb, (const unsigned short*)d_out, deg, (float*)d_out,
            whi1, wlo1, b_conv, whi2, wlo2, b_lin);
    } else {
        // tier3: f32 fallback (round-10 proven)
        int* deg = (int*)d_ws;
        float* normArr = (float*)dstbuf;
        unsigned short* whi1 = (unsigned short*)((char*)dstbuf + 200000);
        unsigned short* wlo1 = (unsigned short*)((char*)dstbuf + 232768);
        unsigned short* whi2 = (unsigned short*)((char*)dstbuf + 265536);
        unsigned short* wlo2 = (unsigned short*)((char*)dstbuf + 298304);
        hipMemsetAsync(deg, 0, (size_t)N_NODES * sizeof(int), stream);
        scatter_kernel<<<ESC_BLOCKS, 256, 0, stream>>>(
            src, (const int*)dstbuf, deg, (unsigned short*)d_out, x, (unsigned short*)d_ws,
            w_conv, w_lin, whi1, wlo1, whi2, wlo2);
        prep_kernel<<<NORM_BLOCKS + WSPLIT_BLOCKS, 256, 0, stream>>>(
            deg, normArr, w_conv, w_lin, whi1, wlo1, whi2, wlo2);
        fused_gather_mlp_f32<<<N_NODES / ROWS, 256, 0, stream>>>(
            x, (const unsigned short*)d_out, normArr, deg, (float*)d_out,
            whi1, wlo1, b_conv, whi2, wlo2, b_lin);
    }
}

// Round 14
// 206.046 us; speedup vs baseline: 1.0878x; 1.0878x over previous
//
#include <hip/hip_runtime.h>

#define N_NODES 50000
#define N_EDGES 800000
#define D 128
#define ROWS 16
#define BCAP 255          // slot cap in a row's 512B out budget (deg max ~45)
#define LCAP 64           // LDS-staged slots per row, power of 2 (P(deg>64) ~ 0)
#define ESC_BLOCKS 3125   // 1 edge/thread: 3125*256 = 800000 exactly
#define XCONV_BLOCKS 3125 // 3125*256*8 = 6.4M floats = x converted to bf16
#define NORM_BLOCKS 196   // fallback path only
#define WSPLIT_BLOCKS 128 // 128*256 = 32768 = 2*D*D
#define XB_OFF 200064     // xb offset in d_ws (16B aligned, past deg)
#define WHI_OFF 13000064  // weight planes in d_ws, past xb (big path)
#define WS_NEEDED 13131136ull

typedef int   v4i __attribute__((ext_vector_type(4)));
typedef float v4f __attribute__((ext_vector_type(4)));

// Buffer map (big path, ws_size >= WS_NEEDED) — round-12 proven layout:
//  d_ws [0, 200000)          : deg (int[50000]) — cursor == final in-degree
//  d_ws [200064, +12.8M)     : xb (bf16 copy of x)
//  d_ws [13000064, +131072)  : whi1/wlo1/whi2/wlo2 (bf16 hi/lo weight planes)
//  d_out                     : per-row 512B: scatter writes src ids (ushort);
//                              fused reads ONLY ITS OWN rows' slots, then
//                              overwrites them => no cross-block hazard.
// Fallback (small ws): round-10 pipeline — normArr+weights in dstbuf, f32 x.
// Round-9 lesson: MFMA B operands come from MEMORY loads only (waitcnt slack).
// Round-13 lesson: scatter is atomic-pipeline bound (~10G/s), NOT contention
// bound — replicated cursors regressed both scatter and fused. Reverted.

__device__ __forceinline__ unsigned short bf_rne(float v) {
    unsigned u = __float_as_uint(v);
    u += 0x7FFFu + ((u >> 16) & 1u);
    return (unsigned short)(u >> 16);
}
__device__ __forceinline__ float bf_up(unsigned short h) {
    return __uint_as_float((unsigned)h << 16);
}
__device__ __forceinline__ void split_pack(float a, float b, unsigned& hw, unsigned& lw) {
    unsigned short ha = bf_rne(a);
    unsigned short hb = bf_rne(b);
    unsigned short la = bf_rne(a - bf_up(ha));
    unsigned short lb = bf_rne(b - bf_up(hb));
    hw = (unsigned)ha | ((unsigned)hb << 16);
    lw = (unsigned)la | ((unsigned)lb << 16);
}
__device__ __forceinline__ unsigned pack2(float a, float b) {
    return (unsigned)bf_rne(a) | ((unsigned)bf_rne(b) << 16);
}
#define UF_LO(v) __uint_as_float((v) << 16)
#define UF_HI(v) __uint_as_float((v) & 0xffff0000u)

// ---- K1: 1-edge/thread scatter + x->bf16 conv + weight split (big path) -----
__global__ void scatter_kernel(const int* __restrict__ src, const int* __restrict__ dst,
                               int* __restrict__ deg, unsigned short* outSlots,
                               const float* __restrict__ x, unsigned short* __restrict__ xb,
                               const float* __restrict__ w1, const float* __restrict__ w2,
                               unsigned short* __restrict__ whi1, unsigned short* __restrict__ wlo1,
                               unsigned short* __restrict__ whi2, unsigned short* __restrict__ wlo2) {
    int b = blockIdx.x, t = threadIdx.x;
    if (b < ESC_BLOCKS) {
        int e = b * 256 + t;  // 3125*256 == N_EDGES exactly
        int s = src[e], d = dst[e];
        int p = atomicAdd(&deg[d], 1);
        if (p < BCAP) outSlots[(size_t)d * 256 + p] = (unsigned short)s;
    } else if (b < ESC_BLOCKS + XCONV_BLOCKS) {
        int i = (b - ESC_BLOCKS) * 256 + t;  // 8 floats each
        float4 a = *(const float4*)(x + (size_t)8 * i);
        float4 c = *(const float4*)(x + (size_t)8 * i + 4);
        uint4 o;
        o.x = pack2(a.x, a.y);
        o.y = pack2(a.z, a.w);
        o.z = pack2(c.x, c.y);
        o.w = pack2(c.z, c.w);
        *(uint4*)(xb + (size_t)8 * i) = o;
    } else {
        int m = (b - ESC_BLOCKS - XCONV_BLOCKS) * 256 + t;  // 0 .. 32767
        int sel = m >> 14;  // 0: w1, 1: w2
        int j = m & 16383;
        float v = sel ? w2[j] : w1[j];
        unsigned short h = bf_rne(v);
        unsigned short lo = bf_rne(v - bf_up(h));
        if (sel) { whi2[j] = h; wlo2[j] = lo; }
        else     { whi1[j] = h; wlo1[j] = lo; }
    }
}

// ---- prep (FALLBACK path only): normArr + weight split into dstbuf ----------
__global__ void prep_kernel(const int* __restrict__ deg, float* __restrict__ normArr,
                            const float* __restrict__ w1, const float* __restrict__ w2,
                            unsigned short* __restrict__ whi1, unsigned short* __restrict__ wlo1,
                            unsigned short* __restrict__ whi2, unsigned short* __restrict__ wlo2) {
    int b = blockIdx.x, t = threadIdx.x;
    if (b < NORM_BLOCKS) {
        int n = b * 256 + t;
        if (n < N_NODES)
            normArr[n] = rsqrtf(fmaxf((float)deg[n], 1.0f));
    } else {
        int m = (b - NORM_BLOCKS) * 256 + t;
        int sel = m >> 14;
        int j = m & 16383;
        float v = sel ? w2[j] : w1[j];
        unsigned short h = bf_rne(v);
        unsigned short lo = bf_rne(v - bf_up(h));
        if (sel) { whi2[j] = h; wlo2[j] = lo; }
        else     { whi1[j] = h; wlo1[j] = lo; }
    }
}

// ======== MFMA MLP phase (round-7/10 proven), shared by both fused paths =====
// 4 waves: wave wv -> col 32-block cb=wv*32 (all 16 rows in the one tile).
// mfma_f32_16x16x32_bf16: A row = lane&15, k = (lane>>4)*8 + i (8 consecutive);
// B col = lane&15, same k;  D col = lane&15, row = (lane>>4)*4 + reg.
#define MLP_BODY                                                               \
    int wv = t >> 6;                                                           \
    int cb = wv << 5;                                                          \
    int l15 = l & 15;                                                          \
    int kq = l >> 4;                                                           \
    const char* phiA = (const char*)&Ahi[l15][0];                              \
    const char* ploA = (const char*)&Alo[l15][0];                              \
    v4i ahi[4], alo[4];                                                        \
_Pragma("unroll")                                                              \
    for (int kt = 0; kt < 4; ++kt) {                                           \
        int off = ((((kt << 2) | kq) ^ l15) << 4);                             \
        ahi[kt] = *(const v4i*)(phiA + off);                                   \
        alo[kt] = *(const v4i*)(ploA + off);                                   \
    }                                                                          \
    __syncthreads();                                                           \
_Pragma("unroll")                                                              \
    for (int ct = 0; ct < 2; ++ct) {                                           \
        int c = cb + (ct << 4) + l15;                                          \
        float bv = b1[c];                                                      \
        v4f acc = {bv, bv, bv, bv};                                            \
        const unsigned short* wh = whi1 + c * D + (kq << 3);                   \
        const unsigned short* wl = wlo1 + c * D + (kq << 3);                   \
_Pragma("unroll")                                                              \
        for (int kt = 0; kt < 4; ++kt) {                                       \
            v4i bh = *(const v4i*)(wh + (kt << 5));                            \
            v4i bl = *(const v4i*)(wl + (kt << 5));                            \
            asm volatile("v_mfma_f32_16x16x32_bf16 %0, %1, %2, %0" : "+v"(acc) : "v"(ahi[kt]), "v"(bh)); \
            asm volatile("v_mfma_f32_16x16x32_bf16 %0, %1, %2, %0" : "+v"(acc) : "v"(alo[kt]), "v"(bh)); \
            asm volatile("v_mfma_f32_16x16x32_bf16 %0, %1, %2, %0" : "+v"(acc) : "v"(ahi[kt]), "v"(bl)); \
        }                                                                      \
        asm volatile("s_nop 7\n\ts_nop 7" : "+v"(acc));                        \
_Pragma("unroll")                                                              \
        for (int r = 0; r < 4; ++r) {                                          \
            float v = fmaxf(acc[r], 0.0f);                                     \
            unsigned short hv = bf_rne(v);                                     \
            unsigned short lv = bf_rne(v - bf_up(hv));                         \
            int ro = (kq << 2) + r;                                            \
            int byte = (2 * c) ^ ((ro & 15) << 4);                             \
            *(unsigned short*)((char*)&Ahi[ro][0] + byte) = hv;                \
            *(unsigned short*)((char*)&Alo[ro][0] + byte) = lv;                \
        }                                                                      \
    }                                                                          \
    __syncthreads();                                                           \
_Pragma("unroll")                                                              \
    for (int kt = 0; kt < 4; ++kt) {                                           \
        int off = ((((kt << 2) | kq) ^ l15) << 4);                             \
        ahi[kt] = *(const v4i*)(phiA + off);                                   \
        alo[kt] = *(const v4i*)(ploA + off);                                   \
    }                                                                          \
_Pragma("unroll")                                                              \
    for (int ct = 0; ct < 2; ++ct) {                                           \
        int c = cb + (ct << 4) + l15;                                          \
        float bv = b2[c];                                                      \
        v4f acc = {bv, bv, bv, bv};                                            \
        const unsigned short* wh = whi2 + c * D + (kq << 3);                   \
        const unsigned short* wl = wlo2 + c * D + (kq << 3);                   \
_Pragma("unroll")                                                              \
        for (int kt = 0; kt < 4; ++kt) {                                       \
            v4i bh = *(const v4i*)(wh + (kt << 5));                            \
            v4i bl = *(const v4i*)(wl + (kt << 5));                            \
            asm volatile("v_mfma_f32_16x16x32_bf16 %0, %1, %2, %0" : "+v"(acc) : "v"(ahi[kt]), "v"(bh)); \
            asm volatile("v_mfma_f32_16x16x32_bf16 %0, %1, %2, %0" : "+v"(acc) : "v"(alo[kt]), "v"(bh)); \
            asm volatile("v_mfma_f32_16x16x32_bf16 %0, %1, %2, %0" : "+v"(acc) : "v"(ahi[kt]), "v"(bl)); \
        }                                                                      \
        asm volatile("s_nop 7\n\ts_nop 7" : "+v"(acc));                        \
_Pragma("unroll")                                                              \
        for (int r = 0; r < 4; ++r) {                                          \
            int ro = row_base + (kq << 2) + r;                                 \
            if (ro < N_NODES)                                                  \
                io[(size_t)ro * D + c] = fmaxf(acc[r], 0.0f);                  \
        }                                                                      \
    }

// -------- fused (bf16-x path): 16-deep prefetched gather + MFMA MLP ----------
__global__ __launch_bounds__(256) void fused_gather_mlp_bf16(
    const unsigned short* __restrict__ xb,
    const unsigned short* slotsIn,      // aliases io — NO restrict
    const int* __restrict__ deg,
    float* io,                          // aliases slotsIn — NO restrict
    const unsigned short* __restrict__ whi1, const unsigned short* __restrict__ wlo1,
    const float* __restrict__ b1,
    const unsigned short* __restrict__ whi2, const unsigned short* __restrict__ wlo2,
    const float* __restrict__ b2) {
    __shared__ __align__(16) unsigned short Ahi[ROWS][D];  // 4 KB
    __shared__ __align__(16) unsigned short Alo[ROWS][D];  // 4 KB
    __shared__ unsigned short colsL[ROWS][LCAP];           // 2 KB
    __shared__ float ncolL[ROWS][LCAP];                    // 4 KB
    __shared__ int degL[ROWS];
    __shared__ int nextRow;
    int row_base = blockIdx.x * ROWS;
    int t = threadIdx.x;
    int tx = t & 31;   // lane in group; feature quad 4*tx..4*tx+3
    int l = t & 63;    // lane in wave

    if (t < ROWS) degL[t] = deg[row_base + t];
    if (t == ROWS) nextRow = 0;
    __syncthreads();

    // ---- staging, batched: 4 independent slot loads, then 4 indep deg loads
    {
        int sarr[4], varr[4];
#pragma unroll
        for (int k = 0; k < 4; ++k) {          // ROWS*LCAP = 1024 = 4*256 exact
            int e2 = t + k * 256;
            int r = e2 >> 6, j = e2 & (LCAP - 1);
            varr[k] = (j < degL[r]);
            sarr[k] = varr[k] ? (int)slotsIn[(size_t)(row_base + r) * 256 + j] : 0;
        }
        float narr[4];
#pragma unroll
        for (int k = 0; k < 4; ++k)
            narr[k] = varr[k] ? rsqrtf(fmaxf((float)deg[sarr[k]], 1.0f)) : 0.f;
#pragma unroll
        for (int k = 0; k < 4; ++k) {
            int e2 = t + k * 256;
            int r = e2 >> 6, j = e2 & (LCAP - 1);
            colsL[r][j] = (unsigned short)sarr[k];
            ncolL[r][j] = narr[k];
        }
    }
    __syncthreads();

    // ---- gather: 8 groups of 32 lanes, work-stealing; 16 loads in flight ----
    for (;;) {
        int rr;
        if (tx == 0) rr = atomicAdd(&nextRow, 1);
        rr = __shfl(rr, l & 32);
        if (rr >= ROWS) break;
        int dr = degL[rr];
        float nr = rsqrtf(fmaxf((float)dr, 1.0f));
        float4 acc = make_float4(0.f, 0.f, 0.f, 0.f);
        int jend = min(dr, LCAP);
        for (int j = 0; j < jend; j += 16) {  // zero-norm pads mask ragged tail
            int s0 = colsL[rr][j + 0],  s1 = colsL[rr][j + 1],  s2 = colsL[rr][j + 2],  s3 = colsL[rr][j + 3];
            int s4 = colsL[rr][j + 4],  s5 = colsL[rr][j + 5],  s6 = colsL[rr][j + 6],  s7 = colsL[rr][j + 7];
            int s8 = colsL[rr][j + 8],  s9 = colsL[rr][j + 9],  sa = colsL[rr][j + 10], sb = colsL[rr][j + 11];
            int sc = colsL[rr][j + 12], sd = colsL[rr][j + 13], se = colsL[rr][j + 14], sf = colsL[rr][j + 15];
            uint2 v0 = *(const uint2*)(xb + (size_t)s0 * D + 4 * tx);
            uint2 v1 = *(const uint2*)(xb + (size_t)s1 * D + 4 * tx);
            uint2 v2 = *(const uint2*)(xb + (size_t)s2 * D + 4 * tx);
            uint2 v3 = *(const uint2*)(xb + (size_t)s3 * D + 4 * tx);
            uint2 v4 = *(const uint2*)(xb + (size_t)s4 * D + 4 * tx);
            uint2 v5 = *(const uint2*)(xb + (size_t)s5 * D + 4 * tx);
            uint2 v6 = *(const uint2*)(xb + (size_t)s6 * D + 4 * tx);
            uint2 v7 = *(const uint2*)(xb + (size_t)s7 * D + 4 * tx);
            uint2 v8 = *(const uint2*)(xb + (size_t)s8 * D + 4 * tx);
            uint2 v9 = *(const uint2*)(xb + (size_t)s9 * D + 4 * tx);
            uint2 va = *(const uint2*)(xb + (size_t)sa * D + 4 * tx);
            uint2 vb = *(const uint2*)(xb + (size_t)sb * D + 4 * tx);
            uint2 vc = *(const uint2*)(xb + (size_t)sc * D + 4 * tx);
            uint2 vd = *(const uint2*)(xb + (size_t)sd * D + 4 * tx);
            uint2 ve = *(const uint2*)(xb + (size_t)se * D + 4 * tx);
            uint2 vf = *(const uint2*)(xb + (size_t)sf * D + 4 * tx);
            float n0 = ncolL[rr][j + 0],  n1 = ncolL[rr][j + 1],  n2 = ncolL[rr][j + 2],  n3 = ncolL[rr][j + 3];
            float n4 = ncolL[rr][j + 4],  n5 = ncolL[rr][j + 5],  n6 = ncolL[rr][j + 6],  n7 = ncolL[rr][j + 7];
            float n8 = ncolL[rr][j + 8],  n9 = ncolL[rr][j + 9],  na = ncolL[rr][j + 10], nb = ncolL[rr][j + 11];
            float nc = ncolL[rr][j + 12], nd = ncolL[rr][j + 13], ne = ncolL[rr][j + 14], nf = ncolL[rr][j + 15];
            acc.x += UF_LO(v0.x) * n0 + UF_LO(v1.x) * n1 + UF_LO(v2.x) * n2 + UF_LO(v3.x) * n3
                   + UF_LO(v4.x) * n4 + UF_LO(v5.x) * n5 + UF_LO(v6.x) * n6 + UF_LO(v7.x) * n7
                   + UF_LO(v8.x) * n8 + UF_LO(v9.x) * n9 + UF_LO(va.x) * na + UF_LO(vb.x) * nb
                   + UF_LO(vc.x) * nc + UF_LO(vd.x) * nd + UF_LO(ve.x) * ne + UF_LO(vf.x) * nf;
            acc.y += UF_HI(v0.x) * n0 + UF_HI(v1.x) * n1 + UF_HI(v2.x) * n2 + UF_HI(v3.x) * n3
                   + UF_HI(v4.x) * n4 + UF_HI(v5.x) * n5 + UF_HI(v6.x) * n6 + UF_HI(v7.x) * n7
                   + UF_HI(v8.x) * n8 + UF_HI(v9.x) * n9 + UF_HI(va.x) * na + UF_HI(vb.x) * nb
                   + UF_HI(vc.x) * nc + UF_HI(vd.x) * nd + UF_HI(ve.x) * ne + UF_HI(vf.x) * nf;
            acc.z += UF_LO(v0.y) * n0 + UF_LO(v1.y) * n1 + UF_LO(v2.y) * n2 + UF_LO(v3.y) * n3
                   + UF_LO(v4.y) * n4 + UF_LO(v5.y) * n5 + UF_LO(v6.y) * n6 + UF_LO(v7.y) * n7
                   + UF_LO(v8.y) * n8 + UF_LO(v9.y) * n9 + UF_LO(va.y) * na + UF_LO(vb.y) * nb
                   + UF_LO(vc.y) * nc + UF_LO(vd.y) * nd + UF_LO(ve.y) * ne + UF_LO(vf.y) * nf;
            acc.w += UF_HI(v0.y) * n0 + UF_HI(v1.y) * n1 + UF_HI(v2.y) * n2 + UF_HI(v3.y) * n3
                   + UF_HI(v4.y) * n4 + UF_HI(v5.y) * n5 + UF_HI(v6.y) * n6 + UF_HI(v7.y) * n7
                   + UF_HI(v8.y) * n8 + UF_HI(v9.y) * n9 + UF_HI(va.y) * na + UF_HI(vb.y) * nb
                   + UF_HI(vc.y) * nc + UF_HI(vd.y) * nd + UF_HI(ve.y) * ne + UF_HI(vf.y) * nf;
        }
        if (dr > LCAP) {  // essentially impossible; correctness fallback
            int je = min(dr, BCAP);
            for (int j = LCAP; j < je; ++j) {
                int s = slotsIn[(size_t)(row_base + rr) * 256 + j];
                float nv = rsqrtf(fmaxf((float)deg[s], 1.0f));
                uint2 v = *(const uint2*)(xb + (size_t)s * D + 4 * tx);
                acc.x += UF_LO(v.x) * nv;
                acc.y += UF_HI(v.x) * nv;
                acc.z += UF_LO(v.y) * nv;
                acc.w += UF_HI(v.y) * nv;
            }
        }
        acc.x *= nr; acc.y *= nr; acc.z *= nr; acc.w *= nr;
        unsigned hw0, lw0, hw1, lw1;
        split_pack(acc.x, acc.y, hw0, lw0);
        split_pack(acc.z, acc.w, hw1, lw1);
        int byte = (8 * tx) ^ ((rr & 15) << 4);
        *(uint2*)((char*)&Ahi[rr][0] + byte) = make_uint2(hw0, hw1);
        *(uint2*)((char*)&Alo[rr][0] + byte) = make_uint2(lw0, lw1);
    }
    __syncthreads();

    MLP_BODY
}

// -------- fused (f32-x fallback): round-10 proven kernel, verbatim -----------
__global__ __launch_bounds__(256) void fused_gather_mlp_f32(
    const float* __restrict__ x,
    const unsigned short* slotsIn,      // aliases io — NO restrict
    const float* __restrict__ normArr, const int* __restrict__ deg,
    float* io,                          // aliases slotsIn — NO restrict
    const unsigned short* __restrict__ whi1, const unsigned short* __restrict__ wlo1,
    const float* __restrict__ b1,
    const unsigned short* __restrict__ whi2, const unsigned short* __restrict__ wlo2,
    const float* __restrict__ b2) {
    __shared__ __align__(16) unsigned short Ahi[ROWS][D];
    __shared__ __align__(16) unsigned short Alo[ROWS][D];
    __shared__ unsigned short colsL[ROWS][LCAP];
    __shared__ float ncolL[ROWS][LCAP];
    __shared__ int degL[ROWS];
    __shared__ int nextRow;
    int row_base = blockIdx.x * ROWS;
    int t = threadIdx.x;
    int tx = t & 31;
    int l = t & 63;

    if (t < ROWS) degL[t] = deg[row_base + t];
    if (t == ROWS) nextRow = 0;
    __syncthreads();

    for (int e2 = t; e2 < ROWS * LCAP; e2 += 256) {
        int r = e2 >> 6;
        int j = e2 & (LCAP - 1);
        if (j < degL[r]) {
            int s = slotsIn[(size_t)(row_base + r) * 256 + j];
            colsL[r][j] = (unsigned short)s;
            ncolL[r][j] = normArr[s];
        } else {
            colsL[r][j] = 0;
            ncolL[r][j] = 0.f;
        }
    }
    __syncthreads();

    for (;;) {
        int rr;
        if (tx == 0) rr = atomicAdd(&nextRow, 1);
        rr = __shfl(rr, l & 32);
        if (rr >= ROWS) break;
        int dr = degL[rr];
        float nr = rsqrtf(fmaxf((float)dr, 1.0f));
        float4 acc = make_float4(0.f, 0.f, 0.f, 0.f);
        int jend = min(dr, LCAP);
        for (int j = 0; j < jend; j += 8) {
            int s0 = colsL[rr][j + 0], s1 = colsL[rr][j + 1], s2 = colsL[rr][j + 2], s3 = colsL[rr][j + 3];
            int s4 = colsL[rr][j + 4], s5 = colsL[rr][j + 5], s6 = colsL[rr][j + 6], s7 = colsL[rr][j + 7];
            float n0 = ncolL[rr][j + 0], n1 = ncolL[rr][j + 1], n2 = ncolL[rr][j + 2], n3 = ncolL[rr][j + 3];
            float n4 = ncolL[rr][j + 4], n5 = ncolL[rr][j + 5], n6 = ncolL[rr][j + 6], n7 = ncolL[rr][j + 7];
            float4 x0 = *(const float4*)(x + (size_t)s0 * D + 4 * tx);
            float4 x1 = *(const float4*)(x + (size_t)s1 * D + 4 * tx);
            float4 x2 = *(const float4*)(x + (size_t)s2 * D + 4 * tx);
            float4 x3 = *(const float4*)(x + (size_t)s3 * D + 4 * tx);
            float4 x4 = *(const float4*)(x + (size_t)s4 * D + 4 * tx);
            float4 x5 = *(const float4*)(x + (size_t)s5 * D + 4 * tx);
            float4 x6 = *(const float4*)(x + (size_t)s6 * D + 4 * tx);
            float4 x7 = *(const float4*)(x + (size_t)s7 * D + 4 * tx);
            acc.x += x0.x * n0 + x1.x * n1 + x2.x * n2 + x3.x * n3
                   + x4.x * n4 + x5.x * n5 + x6.x * n6 + x7.x * n7;
            acc.y += x0.y * n0 + x1.y * n1 + x2.y * n2 + x3.y * n3
                   + x4.y * n4 + x5.y * n5 + x6.y * n6 + x7.y * n7;
            acc.z += x0.z * n0 + x1.z * n1 + x2.z * n2 + x3.z * n3
                   + x4.z * n4 + x5.z * n5 + x6.z * n6 + x7.z * n7;
            acc.w += x0.w * n0 + x1.w * n1 + x2.w * n2 + x3.w * n3
                   + x4.w * n4 + x5.w * n5 + x6.w * n6 + x7.w * n7;
        }
        if (dr > LCAP) {
            int je = min(dr, BCAP);
            for (int j = LCAP; j < je; ++j) {
                int s = slotsIn[(size_t)(row_base + rr) * 256 + j];
                float nv = normArr[s];
                float4 xv = *(const float4*)(x + (size_t)s * D + 4 * tx);
                acc.x += xv.x * nv; acc.y += xv.y * nv;
                acc.z += xv.z * nv; acc.w += xv.w * nv;
            }
        }
        acc.x *= nr; acc.y *= nr; acc.z *= nr; acc.w *= nr;
        unsigned hw0, lw0, hw1, lw1;
        split_pack(acc.x, acc.y, hw0, lw0);
        split_pack(acc.z, acc.w, hw1, lw1);
        int byte = (8 * tx) ^ ((rr & 15) << 4);
        *(uint2*)((char*)&Ahi[rr][0] + byte) = make_uint2(hw0, hw1);
        *(uint2*)((char*)&Alo[rr][0] + byte) = make_uint2(lw0, lw1);
    }
    __syncthreads();

    MLP_BODY
}

extern "C" void kernel_launch(void* const* d_in, const int* in_sizes, int n_in,
                              void* d_out, int out_size, void* d_ws, size_t ws_size,
                              hipStream_t stream) {
    const float* x      = (const float*)d_in[0];
    const int*   src    = (const int*)d_in[1];
    int*         dstbuf = (int*)d_in[2];   // fallback: dead after scatter
    const float* w_conv = (const float*)d_in[3];
    const float* b_conv = (const float*)d_in[4];
    const float* w_lin  = (const float*)d_in[5];
    const float* b_lin  = (const float*)d_in[6];

    int* deg = (int*)d_ws;  // 200,000 B (known-safe size)
    unsigned short* xb = (unsigned short*)((char*)d_ws + XB_OFF);
    const bool big = ws_size >= WS_NEEDED;

    hipMemsetAsync(deg, 0, (size_t)N_NODES * sizeof(int), stream);
    if (big) {
        unsigned short* whi1 = (unsigned short*)((char*)d_ws + WHI_OFF);
        unsigned short* wlo1 = (unsigned short*)((char*)d_ws + WHI_OFF + 32768);
        unsigned short* whi2 = (unsigned short*)((char*)d_ws + WHI_OFF + 65536);
        unsigned short* wlo2 = (unsigned short*)((char*)d_ws + WHI_OFF + 98304);
        scatter_kernel<<<ESC_BLOCKS + XCONV_BLOCKS + WSPLIT_BLOCKS, 256, 0, stream>>>(
            src, (const int*)dstbuf, deg, (unsigned short*)d_out, x, xb,
            w_conv, w_lin, whi1, wlo1, whi2, wlo2);
        fused_gather_mlp_bf16<<<N_NODES / ROWS, 256, 0, stream>>>(
            xb, (const unsigned short*)d_out, deg, (float*)d_out,
            whi1, wlo1, b_conv, whi2, wlo2, b_lin);
    } else {
        float* normArr = (float*)dstbuf;
        unsigned short* whi1 = (unsigned short*)((char*)dstbuf + 200000);
        unsigned short* wlo1 = (unsigned short*)((char*)dstbuf + 232768);
        unsigned short* whi2 = (unsigned short*)((char*)dstbuf + 265536);
        unsigned short* wlo2 = (unsigned short*)((char*)dstbuf + 298304);
        scatter_kernel<<<ESC_BLOCKS, 256, 0, stream>>>(
            src, (const int*)dstbuf, deg, (unsigned short*)d_out, x, xb,
            w_conv, w_lin, whi1, wlo1, whi2, wlo2);
        prep_kernel<<<NORM_BLOCKS + WSPLIT_BLOCKS, 256, 0, stream>>>(
            deg, normArr, w_conv, w_lin, whi1, wlo1, whi2, wlo2);
        fused_gather_mlp_f32<<<N_NODES / ROWS, 256, 0, stream>>>(
            x, (const unsigned short*)d_out, normArr, deg, (float*)d_out,
            whi1, wlo1, b_conv, whi2, wlo2, b_lin);
    }
}